// Round 10
// baseline (737.606 us; speedup 1.0000x reference)
//
#include <hip/hip_runtime.h>
#include <math.h>

// Max-plus DP: out[b,t,k] = x[b,t,k] + max(out[b,t-1,k], out[b,t-1,k-1])
//
// Round-10 structure: ONE BLOCK PER BATCH, 8 waves, LDS handoff.
// Rounds 1-9 showed T_tile ~ 9Kcy invariant under every intra-wave
// schedule (DS shfl vs DPP, drains vs counted vmcnt, ring vs batch reads):
// with 1 wave/CU there is no TLP and every memory latency (staging, agent
// -scope boundary/flag loads, store retirement) is exposed serially.
// Fix: move the pipeline inside a block. 32 blocks x 512 threads; wave w
// owns cols [128w,128w+128), 2 cols/lane (row body identical to the
// verified round-8 kernel). Tile-skewed schedule: at step s wave w does
// tile r=s-w; one __syncthreads per step; boundary column passes via a
// double-buffered LDS array (write step s / read s+1 / overwrite s+2 --
// barrier-separated). Corner value carried in a register. The entire
// cross-block machinery (flags, bws, agent atomics, counted vmcnt,
// global_load_lds) is deleted. x is batch-loaded per tile straight to
// registers (within-step batch: stays in VGPRs; first-load latency is
// hidden by the 7 other waves on the CU).

#define BB 32
#define TT 2048
#define KK 1024
#define NW 8              // waves per block
#define WW 128            // cols per wave (2 per lane)
#define RR 32             // rows per tile
#define NT (TT / RR)      // 64 tiles
#define NSTEP (NT + NW - 1)

__global__ __launch_bounds__(512, 1)
void harddtw_wb(const float* __restrict__ x, float* __restrict__ out)
{
    const int b    = blockIdx.x;
    const int w    = threadIdx.x >> 6;   // wave 0..7
    const int lane = threadIdx.x & 63;
    const bool lz  = (lane == 0);

    const int kc = w * WW + (lane << 1);
    const size_t base = (size_t)b * TT * KK;
    const float* xl     = x   + base + kc;
    float*       olbase = out + base + kc;

    // Boundary handoff: bnd[w][r&1][j] = wave w's lane-63 n1 at row j of
    // tile r. Written step s (=r+w), read by wave w+1 at step s+1,
    // overwritten at step s+2 — all barrier-separated.
    __shared__ float bnd[NW][2][RR];

    float pv0 = 0.0f, pv1 = 0.0f;        // prev-row values (0 => row0 = x)
    float sh_prev = 0.0f;                // left-neighbor pv1 from "row -1"
    float corner = 0.0f;                 // bnd entry 31 of prev tile (row r*32-1)

#pragma unroll 1
    for (int s = 0; s < NSTEP; ++s) {
        const int r = s - w;
        if (r >= 0 && r < NT) {
            // Batch-issue the tile's 32 row loads straight to registers.
            const float* gp = xl + (size_t)r * RR * KK;
            float2 td[RR];
#pragma unroll
            for (int j = 0; j < RR; ++j)
                td[j] = *(const float2*)(gp + (size_t)j * KK);

            // Boundary values for this tile: lane j holds row j's left-
            // boundary (row r*32+j-1 of col w*128-1). Lane 0 = corner.
            float bcur;
            if (w == 0) {
                bcur = -INFINITY;        // col -1 does not exist
            } else {
                float e = (lane >= 1 && lane < RR) ? bnd[w - 1][r & 1][lane - 1]
                                                   : 0.0f;
                bcur = lz ? corner : e;
                corner = bnd[w - 1][r & 1][RR - 1];  // next tile's corner
            }

            float* ol = olbase + (size_t)r * RR * KK;
#pragma unroll
            for (int j = 0; j < RR; ++j) {
                float2 xv = td[j];
                float n1 = xv.y + fmaxf(pv1, pv0);
                float sh_new = __shfl_up(n1, 1);   // consumed next row
                float bv = __int_as_float(
                    __builtin_amdgcn_readlane(__float_as_int(bcur), j));
                float left = lz ? bv : sh_prev;
                float n0 = xv.x + fmaxf(pv0, left);

                float2 o; o.x = n0; o.y = n1;
                *(float2*)ol = o;
                ol += KK;
                if (lane == 63) bnd[w][r & 1][j] = n1;  // publish boundary

                pv0 = n0; pv1 = n1; sh_prev = sh_new;
            }
        }
        __syncthreads();                 // step handoff (includes lgkmcnt)
    }
}

extern "C" void kernel_launch(void* const* d_in, const int* in_sizes, int n_in,
                              void* d_out, int out_size, void* d_ws, size_t ws_size,
                              hipStream_t stream) {
    (void)in_sizes; (void)n_in; (void)out_size; (void)d_ws; (void)ws_size;
    const float* x = (const float*)d_in[0];
    float* out = (float*)d_out;

    harddtw_wb<<<dim3(BB), dim3(NW * 64), 0, stream>>>(x, out);
}

// Round 12
// 630.424 us; speedup vs baseline: 1.1700x; 1.1700x over previous
//
#include <hip/hip_runtime.h>
#include <math.h>

// Max-plus DP: out[b,t,k] = x[b,t,k] + max(out[b,t-1,k], out[b,t-1,k-1])
//
// Round-11 hybrid (resubmit; r11 died on a typo, theory untested):
// 128 blocks = 32 batches x 4 column groups (256 cols); each block 4
// waves x 64 cols (1 col/lane), tile-skewed (wave w does tile r=step-w).
// Combines the independently-verified pieces:
//   - round-10 intra-block pipeline: LDS bnd[][2][32] double-buffer +
//     one __syncthreads per step (passed, zero protocol cost);
//   - round-8 cross-block protocol (bws + flags, agent-scope relaxed
//     atomics) on the 3 links per batch — its spin/drain latency now
//     stalls ONE wave while 3 others keep the CU busy (TLP, which the
//     1-wave/CU rounds 5-9 never had);
//   - round-9 DPP left-shift (pure VALU, passed) — required because at
//     1 col/lane the shift is on the every-row critical path;
//   - rounds 7-9 batch load of the whole tile to registers WITH
//     sched_barrier(0) to pin it (round 10 dropped the barrier and the
//     compiler sank the loads -> per-row exposed latency, VGPR 48).
// 128 CUs active (4x round 10), ~4MB of loads in flight chip-wide.

#define BB 32
#define TT 2048
#define KK 1024
#define NG 4              // column groups (blocks per batch)
#define NW 4              // waves per block
#define WW 64             // cols per wave (1 per lane)
#define GW (NW * WW)      // 256 cols per block
#define RR 32             // rows per tile
#define NT (TT / RR)      // 64 tiles
#define NSTEP (NT + NW - 1)

__global__ __launch_bounds__(256, 1)
void harddtw_hyb(const float* __restrict__ x, float* __restrict__ out,
                 int* __restrict__ flags, float* __restrict__ bws)
{
    const int bid  = blockIdx.x;
    const int g    = bid & (NG - 1);     // column group 0..3
    const int b    = bid >> 2;           // batch
    const int w    = threadIdx.x >> 6;   // wave 0..3
    const int lane = threadIdx.x & 63;
    const bool lz  = (lane == 0);
    const bool l16 = (lane == 16), l32 = (lane == 32), l48 = (lane == 48);

    const int kc = g * GW + w * WW + lane;
    const size_t base = (size_t)b * TT * KK;
    const float* xl  = x + base + kc;
    float*       olb = out + base + kc;

    int* myflag = flags + bid;
    int* upflag = flags + bid - 1;       // same batch, group g-1
    float*       mybw = bws + (size_t)bid * TT;        // we publish (g<3)
    const float* upbw = bws + (size_t)(bid - 1) * TT;  // we consume (g>0)

    // Intra-block boundary handoff: bnd[w][r&1][j] = wave w's lane-63 n at
    // row j of tile r. Written step r+w, read by wave w+1 at step r+w+1,
    // overwritten step r+w+2 — barrier-separated (round-10 verified).
    __shared__ float bnd[NW - 1][2][RR];

    float pv = 0.0f;                     // prev-row value (0 => row0 = x)
    float left_prev = 0.0f;              // prev-row value of col kc-1
    float corner = 0.0f;                 // intra-block corner carry
    float bcur = -INFINITY;              // boundary, lane j = row j-1 of tile
    unsigned long long bp[16];           // wave3/lane63: packed boundary
#pragma unroll
    for (int i = 0; i < 16; ++i) bp[i] = 0ull;

    const bool wpub = (w == NW - 1) && (g < NG - 1);

#pragma unroll 1
    for (int s = 0; s < NSTEP; ++s) {
        const int r = s - w;
        if (r >= 0 && r < NT) {
            // 1. Batch-issue the tile's 32 loads; PIN them hoisted.
            const float* gp = xl + (size_t)r * RR * KK;
            float td[RR];
#pragma unroll
            for (int j = 0; j < RR; ++j)
                td[j] = gp[(size_t)j * KK];
            __builtin_amdgcn_sched_barrier(0);

            // 2. Boundary acquisition (overlaps td load latency).
            if (w == 0) {
                if (g > 0) {
                    while (__hip_atomic_load(upflag, __ATOMIC_RELAXED,
                                             __HIP_MEMORY_SCOPE_AGENT) < r + 1)
                        __builtin_amdgcn_s_sleep(1);
                    __asm__ volatile("" ::: "memory");
                    if (r == 0) {
                        if (lz) bcur = 0.0f;           // virtual row -1
                        else if (lane < RR)
                            bcur = __hip_atomic_load(upbw + lane - 1,
                                       __ATOMIC_RELAXED, __HIP_MEMORY_SCOPE_AGENT);
                    } else {
                        if (lane < RR)                 // lane0 -> row r*32-1
                            bcur = __hip_atomic_load(
                                       upbw + (size_t)r * RR + lane - 1,
                                       __ATOMIC_RELAXED, __HIP_MEMORY_SCOPE_AGENT);
                    }
                }
                // g==0: bcur stays -INF (col -1 doesn't exist)
            } else {
                float e = (lane >= 1 && lane < RR) ? bnd[w - 1][r & 1][lane - 1]
                                                   : 0.0f;
                bcur = lz ? corner : e;
                corner = bnd[w - 1][r & 1][RR - 1];    // next tile's corner
            }

            // 3. Rows: pure-VALU recurrence (DPP shift, round-9 verified).
            float* ol = olb + (size_t)r * RR * KK;
            float bpe = 0.0f;
#pragma unroll
            for (int j = 0; j < RR; ++j) {
                float xv = td[j];
                float bv = __int_as_float(
                    __builtin_amdgcn_readlane(__float_as_int(bcur), j));
                float left = lz ? bv : left_prev;
                float n = xv + fmaxf(pv, left);

                // left for next row: DPP row_shr:1, patch lanes 16/32/48.
                int ni = __float_as_int(n);
                int di = __builtin_amdgcn_update_dpp(ni, ni, 0x111, 0xf, 0xf,
                                                     false);
                float sh = __int_as_float(di);
                float v15 = __int_as_float(__builtin_amdgcn_readlane(ni, 15));
                float v31 = __int_as_float(__builtin_amdgcn_readlane(ni, 31));
                float v47 = __int_as_float(__builtin_amdgcn_readlane(ni, 47));
                if (l16) sh = v15;
                if (l32) sh = v31;
                if (l48) sh = v47;

                *ol = n;                               // plain store
                ol += KK;

                if (w < NW - 1) {
                    if (lane == 63) bnd[w][r & 1][j] = n;
                } else {
                    if ((j & 1) == 0) {
                        bpe = n;
                    } else {
                        union { float f[2]; unsigned long long u; } cv;
                        cv.f[0] = bpe; cv.f[1] = n;
                        bp[j >> 1] = cv.u;
                    }
                }

                pv = n; left_prev = sh;
            }

            // 4. Cross-block publish (wave 3 only; other waves proceed to
            // the barrier — its drain is hidden by their next-step work).
            if (wpub) {
                if (lane == 63) {
                    unsigned long long* bwp =
                        (unsigned long long*)(mybw + (size_t)r * RR);
#pragma unroll
                    for (int i = 0; i < 16; ++i)
                        __hip_atomic_store(bwp + i, bp[i], __ATOMIC_RELAXED,
                                           __HIP_MEMORY_SCOPE_AGENT);
                }
                __asm__ volatile("s_waitcnt vmcnt(0)" ::: "memory");
                if (lz)
                    __hip_atomic_store(myflag, r + 1, __ATOMIC_RELAXED,
                                       __HIP_MEMORY_SCOPE_AGENT);
            }
        }
        __syncthreads();                 // step handoff (covers LDS writes)
    }
}

extern "C" void kernel_launch(void* const* d_in, const int* in_sizes, int n_in,
                              void* d_out, int out_size, void* d_ws, size_t ws_size,
                              hipStream_t stream) {
    (void)in_sizes; (void)n_in; (void)out_size; (void)ws_size;
    const float* x = (const float*)d_in[0];
    float* out = (float*)d_out;
    int* flags = (int*)d_ws;
    float* bws = (float*)((char*)d_ws + 4096);  // [128][2048] floats = 1MB

    // ws is re-poisoned to 0xAA before every timed launch; flags must be 0.
    // bws needs no init: every read is flag-gated behind its producer.
    (void)hipMemsetAsync(flags, 0, BB * NG * sizeof(int), stream);

    harddtw_hyb<<<dim3(BB * NG), dim3(NW * 64), 0, stream>>>(x, out, flags, bws);
}

// Round 13
// 629.621 us; speedup vs baseline: 1.1715x; 1.0013x over previous
//
#include <hip/hip_runtime.h>
#include <math.h>

// Max-plus DP: out[b,t,k] = x[b,t,k] + max(out[b,t-1,k], out[b,t-1,k-1])
//
// Round-13: BATCH-LEVEL TLP. Rounds 5-9 (1 wave/CU) showed ~9Kcy/tile of
// un-overlappable memory dead time; round 12 (4 waves/CU, same batch,
// barrier-coupled) showed TLP of COUPLED waves doesn't help — they all
// stall together. Fix: 512 independent waves = 32 batches x 16 column
// groups, packed 128 blocks x 4 waves, wave w = batch bc*4+w at group g.
// No __syncthreads anywhere; waves in a CU share nothing. Each wave runs
// the round-8-verified cross-block protocol (own flag + own bws row,
// agent-scope relaxed atomics, publish drained by vmcnt(0) — the drain is
// hidden by the other 3 waves' compute) and the round-12-verified row
// body (DPP left-shift, readlane boundary broadcast, batch-loaded tile
// pinned by sched_barrier). 64 cols/wave, 1 col/lane.

#define BB 32
#define TT 2048
#define KK 1024
#define NG 16             // column groups
#define NWB 4             // waves (= batches) per block
#define WW 64             // cols per wave (1 per lane)
#define RR 32             // rows per tile
#define NT (TT / RR)      // 64 tiles

__global__ __launch_bounds__(256, 1)
void harddtw_tlp(const float* __restrict__ x, float* __restrict__ out,
                 int* __restrict__ flags, float* __restrict__ bws)
{
    const int bid  = blockIdx.x;         // 0..127
    const int g    = bid & (NG - 1);     // column group 0..15
    const int bc   = bid >> 4;           // batch cluster 0..7
    const int w    = threadIdx.x >> 6;   // wave 0..3
    const int lane = threadIdx.x & 63;
    const bool lz  = (lane == 0);
    const bool l16 = (lane == 16), l32 = (lane == 32), l48 = (lane == 48);

    const int b  = bc * NWB + w;         // this wave's batch
    const int kc = g * WW + lane;        // this wave's column
    const size_t base = (size_t)b * TT * KK;
    const float* xl  = x + base + kc;
    float*       olb = out + base + kc;

    const int fidx = (b << 4) | g;       // wave-task id: batch-major
    int* myflag = flags + fidx;
    int* upflag = myflag - 1;            // same batch, group g-1
    float*       mybw = bws + (size_t)fidx * TT;   // we publish (g<15)
    const float* upbw = mybw - TT;                 // we consume (g>0)

    const bool pub = (g < NG - 1);

    float pv = 0.0f;                     // prev-row value (0 => row0 = x)
    float left_prev = 0.0f;              // prev-row value of col kc-1
    unsigned long long bp[16];           // lane63: packed boundary pairs
#pragma unroll
    for (int i = 0; i < 16; ++i) bp[i] = 0ull;

#pragma unroll 1
    for (int r = 0; r < NT; ++r) {
        // 1. Batch-issue the tile's 32 loads; PIN them hoisted (r12-
        // verified). Their latency overlaps the flag spin + bcur load.
        const float* gp = xl + (size_t)r * RR * KK;
        float td[RR];
#pragma unroll
        for (int j = 0; j < RR; ++j)
            td[j] = gp[(size_t)j * KK];
        __builtin_amdgcn_sched_barrier(0);

        // 2. Boundary acquisition (agent-scope; r8-verified pattern).
        float bcur = -INFINITY;
        if (g > 0) {
            while (__hip_atomic_load(upflag, __ATOMIC_RELAXED,
                                     __HIP_MEMORY_SCOPE_AGENT) < r + 1)
                __builtin_amdgcn_s_sleep(1);
            __asm__ volatile("" ::: "memory");
            if (r == 0) {
                if (lz) bcur = 0.0f;               // virtual row -1
                else if (lane < RR)
                    bcur = __hip_atomic_load(upbw + lane - 1,
                               __ATOMIC_RELAXED, __HIP_MEMORY_SCOPE_AGENT);
            } else {
                if (lane < RR)                     // lane j -> row r*32+j-1
                    bcur = __hip_atomic_load(
                               upbw + (size_t)r * RR + lane - 1,
                               __ATOMIC_RELAXED, __HIP_MEMORY_SCOPE_AGENT);
            }
        }

        // 3. Rows: pure-VALU recurrence (DPP shift; r9/r12-verified).
        float* ol = olb + (size_t)r * RR * KK;
        float bpe = 0.0f;
#pragma unroll
        for (int j = 0; j < RR; ++j) {
            float xv = td[j];
            float bv = __int_as_float(
                __builtin_amdgcn_readlane(__float_as_int(bcur), j));
            float left = lz ? bv : left_prev;
            float n = xv + fmaxf(pv, left);

            // left for next row: DPP row_shr:1, patch lanes 16/32/48.
            int ni = __float_as_int(n);
            int di = __builtin_amdgcn_update_dpp(ni, ni, 0x111, 0xf, 0xf,
                                                 false);
            float sh = __int_as_float(di);
            float v15 = __int_as_float(__builtin_amdgcn_readlane(ni, 15));
            float v31 = __int_as_float(__builtin_amdgcn_readlane(ni, 31));
            float v47 = __int_as_float(__builtin_amdgcn_readlane(ni, 47));
            if (l16) sh = v15;
            if (l32) sh = v31;
            if (l48) sh = v47;

            *ol = n;                               // plain store
            ol += KK;

            if ((j & 1) == 0) {
                bpe = n;
            } else {
                union { float f[2]; unsigned long long u; } cv;
                cv.f[0] = bpe; cv.f[1] = n;
                bp[j >> 1] = cv.u;                 // lane63's value matters
            }

            pv = n; left_prev = sh;
        }

        // 4. Publish boundary + flag. The vmcnt(0) drain stalls only THIS
        // wave; the other 3 waves on the CU (different batches) keep
        // computing — that TLP is the whole point of this round.
        if (pub) {
            if (lane == 63) {
                unsigned long long* bwp =
                    (unsigned long long*)(mybw + (size_t)r * RR);
#pragma unroll
                for (int i = 0; i < 16; ++i)
                    __hip_atomic_store(bwp + i, bp[i], __ATOMIC_RELAXED,
                                       __HIP_MEMORY_SCOPE_AGENT);
            }
            __asm__ volatile("s_waitcnt vmcnt(0)" ::: "memory");
            if (lz)
                __hip_atomic_store(myflag, r + 1, __ATOMIC_RELAXED,
                                   __HIP_MEMORY_SCOPE_AGENT);
        }
    }
}

extern "C" void kernel_launch(void* const* d_in, const int* in_sizes, int n_in,
                              void* d_out, int out_size, void* d_ws, size_t ws_size,
                              hipStream_t stream) {
    (void)in_sizes; (void)n_in; (void)out_size; (void)ws_size;
    const float* x = (const float*)d_in[0];
    float* out = (float*)d_out;
    int* flags = (int*)d_ws;
    float* bws = (float*)((char*)d_ws + 4096);  // [32*16][2048] floats = 4MB

    // ws is re-poisoned to 0xAA before every timed launch; flags must be 0.
    // bws needs no init: every read is flag-gated behind its producer.
    (void)hipMemsetAsync(flags, 0, BB * NG * sizeof(int), stream);

    harddtw_tlp<<<dim3((BB / NWB) * NG), dim3(NWB * 64), 0, stream>>>(
        x, out, flags, bws);
}

// Round 15
// 557.019 us; speedup vs baseline: 1.3242x; 1.1303x over previous
//
#include <hip/hip_runtime.h>
#include <math.h>

// Max-plus DP: out[b,t,k] = x[b,t,k] + max(out[b,t-1,k], out[b,t-1,k-1])
// 32 batches x 8 column groups = 256 blocks; each block = 4 SPECIALIZED
// waves for ONE (batch,group) task (resubmit of r14: writelane builtin
// does not exist on this toolchain; replaced with lane-predicated select
// of the wave-uniform readlane(63) value — same 1-2 VALU ops/row):
//   w0 = DP wave: the serial recurrence. VMEM ops/tile: 1 boundary store +
//        1 flag store + 1 boundary load (+1 flag prefetch) — down from 66.
//        Round-8 analysis: T_tile ~ 8.6Kcy = 66 VMEM ops x ~130cy single-
//        wave completion gap; the chain wave must stop paying for memory.
//   w1 = stager: global_load_lds x-tiles into double-buffered LDS.
//   w2,w3 = storers: drain DP's output from an LDS ring to HBM.
// Sync: raw s_barrier + lgkmcnt(0) only (NOT __syncthreads: hipcc emits a
// full vmcnt(0) drain before s_barrier, which would re-serialize the
// storers' in-flight stores every phase). 2 barriers per tile (half-tile
// ring). Boundary publish: rows build bndv so lanes 0-31 hold the tile's
// 32 boundary values -> ONE wave-wide agent store.
// Cross-block protocol (flags + bws, agent relaxed, fpre) = round-8
// verified. Row body (shfl_up consumed next row, readlane broadcast) =
// round-8 verified.

#define BB 32
#define TT 2048
#define KK 1024
#define GG 8
#define WW (KK / GG)      // 128 cols per group
#define RR 32             // rows per tile (flag granularity)
#define HH 16             // half-tile rows (obuf ring granularity)
#define NT (TT / RR)      // 64 tiles

typedef __attribute__((address_space(1))) void GV;  // global
typedef __attribute__((address_space(3))) void LV;  // LDS

#define BAR() do {                                              \
    __asm__ volatile("s_waitcnt lgkmcnt(0)" ::: "memory");      \
    __builtin_amdgcn_s_barrier();                               \
    __builtin_amdgcn_sched_barrier(0);                          \
} while (0)

__global__ __launch_bounds__(256, 1)
void harddtw_ws(const float* __restrict__ x, float* __restrict__ out,
                int* __restrict__ flags, float* __restrict__ bws)
{
    const int bid  = blockIdx.x;
    const int g    = bid >> 5;           // column group 0..7
    const int b    = bid & 31;           // batch
    const int w    = threadIdx.x >> 6;   // wave role: 0=DP 1=stager 2,3=storer
    const int lane = threadIdx.x & 63;
    const bool lz  = (lane == 0);

    const int k0 = g * WW;
    const int kc = k0 + (lane << 1);
    const size_t base = (size_t)b * TT * KK;

    int* myflag = flags + bid;
    int* upflag = flags + bid - 32;      // same batch, group g-1
    float*       mybw = bws + ((size_t)(b * GG + g)) * TT;       // publish
    const float* upbw = bws + ((size_t)(b * GG + g - 1)) * TT;   // consume

    __shared__ float xbuf[2][RR * WW];   // 2 x 16KB input tiles
    __shared__ float obuf[2][HH * WW];   // 2 x 8KB output half-tiles

    // Staging addressing (r8-verified): inst i stages rows 2i,2i+1; lane l
    // covers row 2i+(l>>5), float cols [4*(l&31), +4).
    const float* xstage = x + base + k0 + (size_t)(lane >> 5) * KK
                          + ((lane & 31) << 2);

    const bool pub = (g < GG - 1);

    float pv0 = 0.0f, pv1 = 0.0f;        // prev-row values (0 => row0 = x)
    float sh_prev = 0.0f;                // left-neighbor pv1 from "row -1"
    float bcur = -INFINITY, bnxt = -INFINITY;
    int   bndv = 0;                      // lane j = row j's boundary (built)
    int   fpre = 0;                      // prefetched upflag value

    if (w == 1) {                        // stage tile 0
        const float* gp = xstage;
#pragma unroll
        for (int i = 0; i < RR / 2; ++i) {
            __builtin_amdgcn_global_load_lds((GV*)(void*)gp,
                                             (LV*)(void*)&xbuf[0][i * 256],
                                             16, 0, 0);
            gp += 2 * KK;
        }
        __asm__ volatile("s_waitcnt vmcnt(0)" ::: "memory");
    }
    if (w == 0 && g > 0) {               // tile-0 boundary (r8-verified)
        while (__hip_atomic_load(upflag, __ATOMIC_RELAXED,
                                 __HIP_MEMORY_SCOPE_AGENT) < 1)
            __builtin_amdgcn_s_sleep(1);
        __asm__ volatile("" ::: "memory");
        if (lz) bcur = 0.0f;             // virtual row -1
        else if (lane < RR)
            bcur = __hip_atomic_load(upbw + lane - 1, __ATOMIC_RELAXED,
                                     __HIP_MEMORY_SCOPE_AGENT);
    }
    BAR();                               // xbuf[0] ready for all

#pragma unroll 1
    for (int r = 0; r < NT; ++r) {
        const int cur = r & 1;

        // ================= phase 1 =================
        if (w == 0) {
            // rows 0..15 of tile r
            float2 td[HH];
#pragma unroll
            for (int j = 0; j < HH; ++j)
                td[j] = *(const float2*)&xbuf[cur][j * WW + (lane << 1)];
            __builtin_amdgcn_sched_barrier(0);
            float2 ov[HH];
#pragma unroll
            for (int j = 0; j < HH; ++j) {
                float2 xv = td[j];
                float n1 = xv.y + fmaxf(pv1, pv0);
                float sh_new = __shfl_up(n1, 1);       // consumed next row
                float bv = __int_as_float(
                    __builtin_amdgcn_readlane(__float_as_int(bcur), j));
                float left = lz ? bv : sh_prev;
                float n0 = xv.x + fmaxf(pv0, left);
                ov[j].x = n0; ov[j].y = n1;
                {   // lane j records row j's boundary (uniform readlane +
                    // lane-predicated select == writelane, pure VALU)
                    int b63 = __builtin_amdgcn_readlane(__float_as_int(n1), 63);
                    if (lane == j) bndv = b63;
                }
                pv0 = n0; pv1 = n1; sh_prev = sh_new;
            }
#pragma unroll
            for (int j = 0; j < HH; ++j)
                *(float2*)&obuf[0][j * WW + (lane << 1)] = ov[j];
        } else if (w >= 2 && r > 0) {
            // store h1 of tile r-1
            const int sw = w - 2;
            float* ob = out + base
                      + (size_t)((r - 1) * RR + HH + sw * 8) * KK + kc;
#pragma unroll
            for (int i = 0; i < 8; ++i) {
                float2 v = *(const float2*)&obuf[1][(sw * 8 + i) * WW
                                                    + (lane << 1)];
                *(float2*)ob = v;
                ob += KK;
            }
        }
        BAR();

        // ================= phase 2 =================
        if (w == 0) {
            // rows 16..31 of tile r
            float2 td[HH];
#pragma unroll
            for (int j = 0; j < HH; ++j)
                td[j] = *(const float2*)&xbuf[cur][(HH + j) * WW + (lane << 1)];
            __builtin_amdgcn_sched_barrier(0);
            float2 ov[HH];
#pragma unroll
            for (int j = 0; j < HH; ++j) {
                float2 xv = td[j];
                float n1 = xv.y + fmaxf(pv1, pv0);
                float sh_new = __shfl_up(n1, 1);
                float bv = __int_as_float(
                    __builtin_amdgcn_readlane(__float_as_int(bcur), HH + j));
                float left = lz ? bv : sh_prev;
                float n0 = xv.x + fmaxf(pv0, left);
                ov[j].x = n0; ov[j].y = n1;
                {
                    int b63 = __builtin_amdgcn_readlane(__float_as_int(n1), 63);
                    if (lane == HH + j) bndv = b63;
                }
                pv0 = n0; pv1 = n1; sh_prev = sh_new;
            }
#pragma unroll
            for (int j = 0; j < HH; ++j)
                *(float2*)&obuf[1][j * WW + (lane << 1)] = ov[j];

            // publish: ONE wave-wide boundary store, drain it, flag.
            if (pub) {
                if (lane < RR)
                    __hip_atomic_store(mybw + (size_t)r * RR + lane,
                                       __int_as_float(bndv),
                                       __ATOMIC_RELAXED,
                                       __HIP_MEMORY_SCOPE_AGENT);
                __asm__ volatile("s_waitcnt vmcnt(0)" ::: "memory");
                if (lz)
                    __hip_atomic_store(myflag, r + 1, __ATOMIC_RELAXED,
                                       __HIP_MEMORY_SCOPE_AGENT);
            }
            // next tile's boundary (fpre-guarded spin; r8-verified)
            if (g > 0 && r < NT - 1) {
                if (fpre < r + 2) {
                    while (__hip_atomic_load(upflag, __ATOMIC_RELAXED,
                                             __HIP_MEMORY_SCOPE_AGENT) < r + 2)
                        __builtin_amdgcn_s_sleep(1);
                }
                __asm__ volatile("" ::: "memory");
                if (lane < RR)
                    bnxt = __hip_atomic_load(
                               upbw + (size_t)(r + 1) * RR + lane - 1,
                               __ATOMIC_RELAXED, __HIP_MEMORY_SCOPE_AGENT);
                fpre = __hip_atomic_load(upflag, __ATOMIC_RELAXED,
                                         __HIP_MEMORY_SCOPE_AGENT);
            }
            bcur = bnxt;
        } else if (w == 1) {
            if (r < NT - 1) {            // stage tile r+1
                const float* gp = xstage + (size_t)(r + 1) * RR * KK;
                float* lp = &xbuf[cur ^ 1][0];
#pragma unroll
                for (int i = 0; i < RR / 2; ++i) {
                    __builtin_amdgcn_global_load_lds((GV*)(void*)gp,
                                                     (LV*)(void*)(lp + i * 256),
                                                     16, 0, 0);
                    gp += 2 * KK;
                }
                __asm__ volatile("s_waitcnt vmcnt(0)" ::: "memory");
            }
        } else if (w >= 2) {
            // store h0 of tile r
            const int sw = w - 2;
            float* ob = out + base + (size_t)(r * RR + sw * 8) * KK + kc;
#pragma unroll
            for (int i = 0; i < 8; ++i) {
                float2 v = *(const float2*)&obuf[0][(sw * 8 + i) * WW
                                                    + (lane << 1)];
                *(float2*)ob = v;
                ob += KK;
            }
        }
        BAR();
    }

    // tail: store h1 of the last tile
    if (w >= 2) {
        const int sw = w - 2;
        float* ob = out + base
                  + (size_t)((NT - 1) * RR + HH + sw * 8) * KK + kc;
#pragma unroll
        for (int i = 0; i < 8; ++i) {
            float2 v = *(const float2*)&obuf[1][(sw * 8 + i) * WW
                                                + (lane << 1)];
            *(float2*)ob = v;
            ob += KK;
        }
    }
}

extern "C" void kernel_launch(void* const* d_in, const int* in_sizes, int n_in,
                              void* d_out, int out_size, void* d_ws, size_t ws_size,
                              hipStream_t stream) {
    (void)in_sizes; (void)n_in; (void)out_size; (void)ws_size;
    const float* x = (const float*)d_in[0];
    float* out = (float*)d_out;
    int* flags = (int*)d_ws;
    float* bws = (float*)((char*)d_ws + 4096);  // [32*8][2048] floats = 2MB

    // ws is re-poisoned to 0xAA before every timed launch; flags must be 0.
    // bws needs no init: every read is flag-gated behind its producer.
    (void)hipMemsetAsync(flags, 0, BB * GG * sizeof(int), stream);

    harddtw_ws<<<dim3(BB * GG), dim3(256), 0, stream>>>(x, out, flags, bws);
}